// Round 10
// baseline (3867.475 us; speedup 1.0000x reference)
//
#include <hip/hip_runtime.h>
#include <hip/hip_bf16.h>

// Problem constants
constexpr int kB  = 128;   // batch
constexpr int kW  = 64;    // time steps
constexpr int kM  = 512;   // "major" dim
constexpr int kH  = 64;    // GRU hidden
constexpr int kC  = 4;
constexpr int kLR = 16;
constexpr int kRD = 32;
constexpr int kD  = 128;   // L*H
constexpr int kNC = kB * kM;      // 65536 cells
constexpr int kN  = kM + kC * kLR; // 576 GEMM cols (G | Aw^T)

typedef __attribute__((ext_vector_type(8))) short bf16x8;
typedef __attribute__((ext_vector_type(4))) float f32x4;

__device__ __forceinline__ float sigmf(float v) { return 1.f / (1.f + __expf(-v)); }
__device__ __forceinline__ float tanhf2(float v) { float e = __expf(2.f * v); return 1.f - 2.f / (e + 1.f); }

__device__ __forceinline__ unsigned short f2bfu(float f) {
    union { __hip_bfloat16 h; unsigned short u; } cv; cv.h = __float2bfloat16(f); return cv.u;
}
__device__ __forceinline__ float bfu2f(unsigned short s) {
    return __uint_as_float(((unsigned)s) << 16);
}

__device__ __forceinline__ void gl_lds16(const void* g, void* s) {
    __builtin_amdgcn_global_load_lds(
        (const __attribute__((address_space(1))) void*)(g),
        (__attribute__((address_space(3))) void*)(s), 16, 0, 0);
}

// ---------------- prologue kernels ----------------

// HcG[cell][j] = bf16(H_init[0, m, j])   (cell = b*512 + m)
__global__ void k_initHc(const float* __restrict__ Hini, __hip_bfloat16* __restrict__ HcG) {
    int id = blockIdx.x * 256 + threadIdx.x;          // 65536*64
    int cell = id >> 6, j = id & 63;
    int m = cell & (kM - 1);
    HcG[id] = __float2bfloat16(Hini[m * kH + j]);
}

// H1b[m][j] = bf16(H_init[1, m, j])
__global__ void k_h1b(const float* __restrict__ Hini, __hip_bfloat16* __restrict__ H1b) {
    int id = blockIdx.x * 256 + threadIdx.x;          // 512*64
    H1b[id] = __float2bfloat16(Hini[(kM + (id >> 6)) * kH + (id & 63)]);
}

// gh1T[k][m] = bh1[k] + sum_j H_init[1,m,j] * wh1[k,j]   (f32, fixed over t)
__global__ void k_gh1T(const float* __restrict__ Hini, const float* __restrict__ wh1,
                       const float* __restrict__ bh1, float* __restrict__ gh1T) {
    int id = blockIdx.x * 256 + threadIdx.x;          // 192*512
    int k = id >> 9, m = id & (kM - 1);
    float acc = bh1[k];
    #pragma unroll
    for (int j = 0; j < kH; j++)
        acc = fmaf(Hini[(kM + m) * kH + j], wh1[k * kH + j], acc);
    gh1T[id] = acc;
}

// W0g[192][64] = bf16(wh0); W1x[192][64] = bf16(wx1)
__global__ void k_packW(const float* __restrict__ wh0, const float* __restrict__ wx1,
                        __hip_bfloat16* __restrict__ W0g, __hip_bfloat16* __restrict__ W1x) {
    int id = blockIdx.x * 256 + threadIdx.x;          // 192*64 = 12288
    W0g[id] = __float2bfloat16(wh0[id]);
    W1x[id] = __float2bfloat16(wx1[id]);
}

// BT[n][k] = G[k][n] in bf16 for n<512 (GEMM B pre-transposed, k contiguous)
__global__ void k_buildGT(const float* __restrict__ G, __hip_bfloat16* __restrict__ BT) {
    int id = blockIdx.x * 256 + threadIdx.x;          // 512*512
    int n = id >> 9, k = id & (kM - 1);
    BT[n * kM + k] = __float2bfloat16(G[k * kM + n]);
}

// weight-norm A into BT rows 512..575: BT[512+cl][m] = A_g*A_v/||A_v|| (bf16)
__global__ void k_norm_aw(const float* __restrict__ Av, const float* __restrict__ Ag,
                          __hip_bfloat16* __restrict__ BT) {
    int row = blockIdx.x;        // 0..63 = c*16+l
    int lane = threadIdx.x;      // 64
    float v[8]; float s = 0.f;
    #pragma unroll
    for (int q = 0; q < 8; q++) { v[q] = Av[row * kM + q * 64 + lane]; s += v[q] * v[q]; }
    #pragma unroll
    for (int off = 32; off > 0; off >>= 1) s += __shfl_down(s, off);
    s = __shfl(s, 0);
    float scale = Ag[row] / sqrtf(s);
    #pragma unroll
    for (int q = 0; q < 8; q++)
        BT[(kM + row) * kM + q * 64 + lane] = __float2bfloat16(v[q] * scale);
}

// weight-norm B -> bf16 [c*512+m][32]: l<16 = Bw, l==16 = B_b, rest 0
__global__ void k_norm_bw(const float* __restrict__ Bv, const float* __restrict__ Bg,
                          const float* __restrict__ Bb, __hip_bfloat16* __restrict__ BwNh) {
    int row = blockIdx.x * 256 + threadIdx.x;   // 0..2047 = c*512+m
    float v[16]; float s = 0.f;
    #pragma unroll
    for (int l = 0; l < 16; l++) { v[l] = Bv[row * 16 + l]; s += v[l] * v[l]; }
    float scale = Bg[row] / sqrtf(s);
    #pragma unroll
    for (int l = 0; l < 16; l++) BwNh[row * 32 + l] = __float2bfloat16(v[l] * scale);
    BwNh[row * 32 + 16] = __float2bfloat16(Bb[row]);
    #pragma unroll
    for (int l = 17; l < 32; l++) BwNh[row * 32 + l] = __float2bfloat16(0.f);
}

// weight-norm C -> bf16 [c*32+r][128 d] (natural C_v layout)
__global__ void k_norm_cw(const float* __restrict__ Cv, const float* __restrict__ Cg,
                          __hip_bfloat16* __restrict__ CwB) {
    int row = blockIdx.x;        // 0..127 = c*32+r
    int lane = threadIdx.x;      // 64
    float v0 = Cv[row * kD + lane], v1 = Cv[row * kD + 64 + lane];
    float s = v0 * v0 + v1 * v1;
    #pragma unroll
    for (int off = 32; off > 0; off >>= 1) s += __shfl_down(s, off);
    s = __shfl(s, 0);
    float scale = Cg[row] / sqrtf(s);
    CwB[row * kD + lane] = __float2bfloat16(v0 * scale);
    CwB[row * kD + 64 + lane] = __float2bfloat16(v1 * scale);
}

// ---------------- MFMA GRU step ----------------
// Grid dim3(128 b, 4 mq): linear blk = b + 128*mq -> XCD = b%8, SAME as k_tail's
// (b, mseg) mapping -> XPT/HcG stay in the producer XCD's L2 for the consumer.
// 512 threads = 8 waves; block owns 128 cells; wave owns 16 cells (all 192 gates).
__global__ __launch_bounds__(512) void k_gru(
    const float* __restrict__ x,
    __hip_bfloat16* __restrict__ HcG,        // [65536][64] state in/out
    const __hip_bfloat16* __restrict__ H1b,  // [512][64] h01 table
    const __hip_bfloat16* __restrict__ W0g,  // [192][64] wh0
    const __hip_bfloat16* __restrict__ W1x,  // [192][64] wx1
    const float* __restrict__ gh1T,          // [192][512] f32
    const float* __restrict__ wx0, const float* __restrict__ bx0,
    const float* __restrict__ bh0, const float* __restrict__ bx1,
    __hip_bfloat16* __restrict__ XPT, int t)
{
    __shared__ __align__(16) short W0s[192 * 64];    // 24KB
    __shared__ __align__(16) short W1s[192 * 64];    // 24KB
    __shared__ __align__(16) short HlS[128 * 64];    // 16KB
    __shared__ float xsh[128];

    const int tid = threadIdx.x;
    const int w = tid >> 6, lane = tid & 63;
    const int lr = lane & 15, lq = lane >> 4;
    const int b = blockIdx.x;
    const int mBlk = blockIdx.y * 128;
    const unsigned short* HcU = (const unsigned short*)HcG;
    const unsigned short* H1U = (const unsigned short*)H1b;
    const size_t cellBase = (size_t)b * kM + mBlk;

    // ---- stage weights (gl_lds16, XOR chunk-swizzle on global source) ----
    #pragma unroll
    for (int it = 0; it < 3; it++) {                  // W0s: 1536 chunks
        int cid = it * 512 + tid; int row = cid >> 3, c = cid & 7;
        gl_lds16(W0g + row * 64 + ((c ^ (row & 7)) * 8), W0s + cid * 8);
    }
    #pragma unroll
    for (int it = 0; it < 3; it++) {                  // W1s: 1536 chunks
        int cid = it * 512 + tid; int row = cid >> 3, c = cid & 7;
        gl_lds16(W1x + row * 64 + ((c ^ (row & 7)) * 8), W1s + cid * 8);
    }
    if (tid < 128) xsh[tid] = x[((size_t)b * kW + t) * kM + mBlk + tid];
    __syncthreads();

    const int cl = w * 16 + lr;      // A-fragment row (cell) for this lane

    // ---- Layer 0 MFMA: 12 gate-tiles x K=64 (h_prev direct from global) ----
    bf16x8 a0[2];
    a0[0] = *(const bf16x8*)&HcU[(cellBase + cl) * 64 + lq * 8];
    a0[1] = *(const bf16x8*)&HcU[(cellBase + cl) * 64 + (4 + lq) * 8];
    f32x4 aR[4] = {}, aZ[4] = {}, aN[4] = {};
    #pragma unroll
    for (int kc = 0; kc < 2; kc++) {
        #pragma unroll
        for (int gt = 0; gt < 4; gt++) {
            const int gR = gt * 16 + lr;
            const int gZ = 64 + gt * 16 + lr;
            const int gN = 128 + gt * 16 + lr;
            bf16x8 bR = *(const bf16x8*)&W0s[gR * 64 + (((kc * 4 + lq) ^ (gR & 7)) * 8)];
            bf16x8 bZ = *(const bf16x8*)&W0s[gZ * 64 + (((kc * 4 + lq) ^ (gZ & 7)) * 8)];
            bf16x8 bN = *(const bf16x8*)&W0s[gN * 64 + (((kc * 4 + lq) ^ (gN & 7)) * 8)];
            aR[gt] = __builtin_amdgcn_mfma_f32_16x16x32_bf16(a0[kc], bR, aR[gt], 0, 0, 0);
            aZ[gt] = __builtin_amdgcn_mfma_f32_16x16x32_bf16(a0[kc], bZ, aZ[gt], 0, 0, 0);
            aN[gt] = __builtin_amdgcn_mfma_f32_16x16x32_bf16(a0[kc], bN, aN[gt], 0, 0, 0);
        }
    }

    // ---- Layer 0 combine (per-lane: cells lq*4+r2, unit i = gt*16+lr) ----
    #pragma unroll
    for (int gt = 0; gt < 4; gt++) {
        const int i = gt * 16 + lr;
        const float wxr = wx0[i], wxz = wx0[64 + i], wxn = wx0[128 + i];
        const float bsr = bx0[i] + bh0[i];
        const float bsz = bx0[64 + i] + bh0[64 + i];
        const float bxn = bx0[128 + i], bhn = bh0[128 + i];
        unsigned short hu[4];
        #pragma unroll
        for (int r2 = 0; r2 < 4; r2++) {
            const int clr = w * 16 + lq * 4 + r2;
            const float xv = xsh[clr];
            float rr = sigmf(aR[gt][r2] + bsr + xv * wxr);
            float zz = sigmf(aZ[gt][r2] + bsz + xv * wxz);
            float nn = tanhf2(bxn + xv * wxn + rr * (aN[gt][r2] + bhn));
            float hp = bfu2f(HcU[(cellBase + clr) * 64 + i]);  // own wave's cell: no hazard
            float h1 = nn + zz * (hp - nn);
            unsigned short u = f2bfu(h1);
            HlS[clr * 64 + (((i >> 3) ^ (clr & 7)) * 8) + (i & 7)] = (short)u;
            hu[r2] = u;
        }
        ushort4 pk; pk.x = hu[0]; pk.y = hu[1]; pk.z = hu[2]; pk.w = hu[3];
        *(ushort4*)((unsigned short*)XPT + (size_t)(b * 128 + i) * kM + mBlk + w * 16 + lq * 4) = pk;
    }

    // ---- Layer 1 MFMA: K=64 (h1 @ wx1^T); hidden side via gh1T table ----
    bf16x8 a1[2];
    a1[0] = *(const bf16x8*)&HlS[cl * 64 + ((lq ^ (cl & 7)) * 8)];
    a1[1] = *(const bf16x8*)&HlS[cl * 64 + (((4 + lq) ^ (cl & 7)) * 8)];
    f32x4 cR[4] = {}, cZ[4] = {}, cN[4] = {};
    #pragma unroll
    for (int kc = 0; kc < 2; kc++) {
        #pragma unroll
        for (int gt = 0; gt < 4; gt++) {
            const int gR = gt * 16 + lr;
            const int gZ = 64 + gt * 16 + lr;
            const int gN = 128 + gt * 16 + lr;
            bf16x8 bR = *(const bf16x8*)&W1s[gR * 64 + (((kc * 4 + lq) ^ (gR & 7)) * 8)];
            bf16x8 bZ = *(const bf16x8*)&W1s[gZ * 64 + (((kc * 4 + lq) ^ (gZ & 7)) * 8)];
            bf16x8 bN = *(const bf16x8*)&W1s[gN * 64 + (((kc * 4 + lq) ^ (gN & 7)) * 8)];
            cR[gt] = __builtin_amdgcn_mfma_f32_16x16x32_bf16(a1[kc], bR, cR[gt], 0, 0, 0);
            cZ[gt] = __builtin_amdgcn_mfma_f32_16x16x32_bf16(a1[kc], bZ, cZ[gt], 0, 0, 0);
            cN[gt] = __builtin_amdgcn_mfma_f32_16x16x32_bf16(a1[kc], bN, cN[gt], 0, 0, 0);
        }
    }

    // ---- Layer 1 combine (gh1T f32 table holds H1init@wh1^T + bh1) ----
    const int mb4 = mBlk + w * 16 + lq * 4;
    #pragma unroll
    for (int gt = 0; gt < 4; gt++) {
        const int i = gt * 16 + lr;
        const float bxr = bx1[i], bxz = bx1[64 + i], bxn = bx1[128 + i];
        f32x4 gr4 = *(const f32x4*)&gh1T[(size_t)i * kM + mb4];
        f32x4 gz4 = *(const f32x4*)&gh1T[(size_t)(64 + i) * kM + mb4];
        f32x4 gn4 = *(const f32x4*)&gh1T[(size_t)(128 + i) * kM + mb4];
        unsigned short hu[4];
        #pragma unroll
        for (int r2 = 0; r2 < 4; r2++) {
            const int clr = w * 16 + lq * 4 + r2;
            float rr = sigmf(cR[gt][r2] + bxr + gr4[r2]);
            float zz = sigmf(cZ[gt][r2] + bxz + gz4[r2]);
            float nn = tanhf2(cN[gt][r2] + bxn + rr * gn4[r2]);
            float h01 = bfu2f(H1U[(size_t)(mBlk + clr) * 64 + i]);
            float h2 = nn + zz * (h01 - nn);
            unsigned short u = f2bfu(h2);
            hu[r2] = u;
            ((unsigned short*)HcG)[(cellBase + clr) * 64 + i] = u;   // next-step state
        }
        ushort4 pk; pk.x = hu[0]; pk.y = hu[1]; pk.z = hu[2]; pk.w = hu[3];
        *(ushort4*)((unsigned short*)XPT + (size_t)(b * 128 + 64 + i) * kM + mBlk + w * 16 + lq * 4) = pk;
    }
}

// ---------------- fused GEMM + tail ----------------
// Grid dim3(128 b, 8 mseg): XCD = b%8, matches k_gru's producer mapping.
// BK=32 double-buffer (2x16KB) with tail buffers fully aliased -> 48KB LDS
// -> 3 blocks/CU. Chunk swizzle c^((row>>1)&3) keeps fragment reads 2-way.
__global__ __launch_bounds__(256) void k_tail(
    const __hip_bfloat16* __restrict__ X,    // XPT [b*128+d][512]
    const __hip_bfloat16* __restrict__ BT,   // [576][512]
    const float* __restrict__ Ab,
    const __hip_bfloat16* __restrict__ BwNh, // [c*512+m][32]
    const __hip_bfloat16* __restrict__ CwB,  // [c*32+r][128]
    const float* __restrict__ Cb, const float* __restrict__ FRw,
    const float* __restrict__ FRb, float* __restrict__ OUT, int t)
{
    __shared__ __align__(16) short SM[24576];        // 48KB
    // buf(i) = SM + i*8192: A [128 rows][32 k] (4096) then B [128 cols][32 k] (4096)
    short* xp0L = SM;                // [64 m][128 d]  16KB (aliases buf0)
    short* aL   = SM + 8192;         // [128 d][64 cl] 16KB (aliases buf1)
    short* Xr   = SM + 16384;        // [4 waves][16 m][128 d] 16KB

    const int tid = threadIdx.x;
    const int b = blockIdx.x, mseg = blockIdx.y;
    const int w = tid >> 6, lane = tid & 63;
    const int lr = lane & 15, lq = lane >> 4;
    const int wm = w >> 1, wn = w & 1;

    f32x4 acc[4][4] = {};
    const __hip_bfloat16* Xb = X + (size_t)b * 128 * kM;

    auto STAGE = [&](int kk, int buf) {
        short* AsB = SM + buf * 8192;
        short* BsB = AsB + 4096;
        #pragma unroll
        for (int it = 0; it < 2; it++) {             // A: 128 rows x 4 chunks = 512
            int cid = it * 256 + tid;
            int row = cid >> 2, ch = cid & 3;
            int cg = ch ^ ((row >> 1) & 3);
            gl_lds16(Xb + (size_t)row * kM + kk + cg * 8, AsB + cid * 8);
        }
        #pragma unroll
        for (int it = 0; it < 2; it++) {             // B: 128 cols x 4 chunks = 512
            int cid = it * 256 + tid;
            int j = cid >> 2, ch = cid & 3;
            int cg = ch ^ ((j >> 1) & 3);
            int n = (j < 64) ? (mseg * 64 + j) : (448 + j);
            gl_lds16(BT + (size_t)n * kM + kk + cg * 8, BsB + cid * 8);
        }
    };

    STAGE(0, 0);
    __syncthreads();          // buf0 ready

    int cur = 0;
    for (int ki = 0; ki < 16; ki++) {
        if (ki < 15) STAGE((ki + 1) * 32, cur ^ 1);  // next tile in flight over compute
        const short* AsB = SM + cur * 8192;
        const short* BsB = AsB + 4096;
        bf16x8 af[4], bfr[4];
        #pragma unroll
        for (int fi = 0; fi < 4; fi++) {
            int row = wm * 64 + fi * 16 + lr;
            af[fi] = *(const bf16x8*)&AsB[row * 32 + ((lq ^ ((row >> 1) & 3)) * 8)];
        }
        #pragma unroll
        for (int fj = 0; fj < 4; fj++) {
            int col = wn * 64 + fj * 16 + lr;
            bfr[fj] = *(const bf16x8*)&BsB[col * 32 + ((lq ^ ((col >> 1) & 3)) * 8)];
        }
        #pragma unroll
        for (int fi = 0; fi < 4; fi++)
            #pragma unroll
            for (int fj = 0; fj < 4; fj++)
                acc[fi][fj] = __builtin_amdgcn_mfma_f32_16x16x32_bf16(
                    af[fi], bfr[fj], acc[fi][fj], 0, 0, 0);
        __syncthreads();      // waves done with buf[cur]; next buf staged (vmcnt drained)
        cur ^= 1;
    }

    // ---- scatter C tile to LDS (buffers now free; aliased by xp0L/aL) ----
    if (wn == 0) {
        // m-cols -> relu -> xp0L[m][d], packed 4 d per uint2, chunk-XOR by (m&7)
        #pragma unroll
        for (int fi = 0; fi < 4; fi++) {
            const int d0 = wm * 64 + fi * 16 + lq * 4;
            const int c16 = d0 >> 3, half = lq & 1;
            #pragma unroll
            for (int fj = 0; fj < 4; fj++) {
                const int ml = fj * 16 + lr;
                unsigned lo = (unsigned)f2bfu(fmaxf(acc[fi][fj][0], 0.f)) |
                              ((unsigned)f2bfu(fmaxf(acc[fi][fj][1], 0.f)) << 16);
                unsigned hi = (unsigned)f2bfu(fmaxf(acc[fi][fj][2], 0.f)) |
                              ((unsigned)f2bfu(fmaxf(acc[fi][fj][3], 0.f)) << 16);
                uint2 pk; pk.x = lo; pk.y = hi;
                *(uint2*)&xp0L[ml * 128 + ((c16 ^ (ml & 7)) * 8) + half * 4] = pk;
            }
        }
    } else {
        // a-cols -> +A_b -> aL[d][cl], scalar bf16, chunk-XOR by (d&7)
        #pragma unroll
        for (int fj = 0; fj < 4; fj++) {
            const int clc = fj * 16 + lr;
            const float ab = Ab[clc];
            #pragma unroll
            for (int fi = 0; fi < 4; fi++) {
                #pragma unroll
                for (int r = 0; r < 4; r++) {
                    const int d = wm * 64 + fi * 16 + lq * 4 + r;
                    aL[d * 64 + (((clc >> 3) ^ (d & 7)) * 8) + (clc & 7)] =
                        (short)f2bfu(acc[fi][fj][r] + ab);
                }
            }
        }
    }
    __syncthreads();

    // ---- tail: wave w = channel c ----
    const int c = w;
    bf16x8 af2[8];
    #pragma unroll
    for (int dt = 0; dt < 8; dt++) {
        bf16x8 v = {};
        const int d = dt * 16 + lr;
        if (lq < 2) {
            v = *(const bf16x8*)&aL[d * 64 + (((c * 2 + lq) ^ (d & 7)) * 8)];
        } else if (lq == 2) {
            v[0] = (short)0x3F80;          // 1.0 at k=16 -> bias column
        }
        af2[dt] = v;
    }
    bf16x8 cwf[2][4];
    #pragma unroll
    for (int rt = 0; rt < 2; rt++)
        #pragma unroll
        for (int s = 0; s < 4; s++)
            cwf[rt][s] = *(const bf16x8*)&CwB[((size_t)(c * kRD + rt * 16 + lr)) * kD + s * 32 + lq * 8];
    const float cbv0 = Cb[c * kRD + lr];
    const float cbv1 = Cb[c * kRD + 16 + lr];
    short* Xrw = Xr + w * 2048;

    for (int mt = 0; mt < 4; mt++) {
        const int mg = mseg * 64 + mt * 16 + lr;     // global m (B-frag col)
        bf16x8 bf1 = *(const bf16x8*)&BwNh[((size_t)c * kM + mg) * 32 + lq * 8];
        f32x4 acc1[8] = {};
        #pragma unroll
        for (int dt = 0; dt < 8; dt++)
            acc1[dt] = __builtin_amdgcn_mfma_f32_16x16x32_bf16(af2[dt], bf1, acc1[dt], 0, 0, 0);

        // + x_p0, relu, pack -> Xr (wave-private)
        const int mlT = mt * 16 + lr;                // xp0L row
        #pragma unroll
        for (int dt = 0; dt < 8; dt++) {
            const int c16 = dt * 2 + (lq >> 1), half = lq & 1;
            uint2 xv = *(const uint2*)&xp0L[mlT * 128 + ((c16 ^ (mlT & 7)) * 8) + half * 4];
            float x0 = bfu2f((unsigned short)(xv.x & 0xFFFF));
            float x1 = bfu2f((unsigned short)(xv.x >> 16));
            float x2 = bfu2f((unsigned short)(xv.y & 0xFFFF));
            float x3 = bfu2f((unsigned short)(xv.y >> 16));
            unsigned lo = (unsigned)f2bfu(fmaxf(acc1[dt][0] + x0, 0.f)) |
                          ((unsigned)f2bfu(fmaxf(acc1[dt][1] + x1, 0.f)) << 16);
            unsigned hi = (unsigned)f2bfu(fmaxf(acc1[dt][2] + x2, 0.f)) |
                          ((unsigned)f2bfu(fmaxf(acc1[dt][3] + x3, 0.f)) << 16);
            uint2 pk; pk.x = lo; pk.y = hi;
            *(uint2*)&Xrw[lr * 128 + ((c16 ^ (lr & 7)) * 8) + half * 4] = pk;
        }

        // stage 2: y-logits + sigmoid + FR dot
        bf16x8 xa[4];
        #pragma unroll
        for (int s = 0; s < 4; s++)
            xa[s] = *(const bf16x8*)&Xrw[lr * 128 + (((s * 4 + lq) ^ (lr & 7)) * 8)];
        float po0 = 0.f, po1 = 0.f, po2 = 0.f, po3 = 0.f;
        const int mrow = mseg * 64 + mt * 16 + lq * 4;
        #pragma unroll
        for (int rt = 0; rt < 2; rt++) {
            f32x4 a2 = {};
            #pragma unroll
            for (int s = 0; s < 4; s++)
                a2 = __builtin_amdgcn_mfma_f32_16x16x32_bf16(xa[s], cwf[rt][s], a2, 0, 0, 0);
            const float cb = rt ? cbv1 : cbv0;
            const int r = rt * 16 + lr;
            po0 = fmaf(sigmf(a2[0] + cb), FRw[((size_t)c * kM + mrow + 0) * kRD + r], po0);
            po1 = fmaf(sigmf(a2[1] + cb), FRw[((size_t)c * kM + mrow + 1) * kRD + r], po1);
            po2 = fmaf(sigmf(a2[2] + cb), FRw[((size_t)c * kM + mrow + 2) * kRD + r], po2);
            po3 = fmaf(sigmf(a2[3] + cb), FRw[((size_t)c * kM + mrow + 3) * kRD + r], po3);
        }
        #pragma unroll
        for (int off = 8; off > 0; off >>= 1) {
            po0 += __shfl_xor(po0, off);
            po1 += __shfl_xor(po1, off);
            po2 += __shfl_xor(po2, off);
            po3 += __shfl_xor(po3, off);
        }
        if (lr == 0) {
            const float* frb = &FRb[c * kM + mrow];
            float4 o;
            o.x = po0 + frb[0]; o.y = po1 + frb[1];
            o.z = po2 + frb[2]; o.w = po3 + frb[3];
            *(float4*)&OUT[((size_t)(c * kB + b) * kW + t) * kM + mrow] = o;
        }
    }
}

// ---------------- launch ----------------
extern "C" void kernel_launch(void* const* d_in, const int* in_sizes, int n_in,
                              void* d_out, int out_size, void* d_ws, size_t ws_size,
                              hipStream_t stream) {
    const float* x    = (const float*)d_in[0];
    const float* Hini = (const float*)d_in[1];
    const float* G    = (const float*)d_in[2];
    const float* wx0  = (const float*)d_in[3];
    const float* wh0  = (const float*)d_in[4];
    const float* bx0  = (const float*)d_in[5];
    const float* bh0  = (const float*)d_in[6];
    const float* wx1  = (const float*)d_in[7];
    const float* wh1  = (const float*)d_in[8];
    const float* bx1  = (const float*)d_in[9];
    const float* bh1  = (const float*)d_in[10];
    const float* A_v  = (const float*)d_in[11];
    const float* A_g  = (const float*)d_in[12];
    const float* A_b  = (const float*)d_in[13];
    const float* B_v  = (const float*)d_in[14];
    const float* B_g  = (const float*)d_in[15];
    const float* B_b  = (const float*)d_in[16];
    const float* C_v  = (const float*)d_in[17];
    const float* C_g  = (const float*)d_in[18];
    const float* C_b  = (const float*)d_in[19];
    const float* FR_w = (const float*)d_in[20];
    const float* FR_b = (const float*)d_in[21];
    float* out = (float*)d_out;

    char* w = (char*)d_ws;
    __hip_bfloat16* HcG  = (__hip_bfloat16*)w; w += (size_t)kNC * 64 * 2;   // 8MB
    __hip_bfloat16* XPT  = (__hip_bfloat16*)w; w += (size_t)128 * kNC * 2;  // 16MB
    __hip_bfloat16* BT   = (__hip_bfloat16*)w; w += (size_t)kN * kM * 2;    // 576KB
    __hip_bfloat16* H1b  = (__hip_bfloat16*)w; w += (size_t)kM * kH * 2;    // 64KB
    __hip_bfloat16* W0g  = (__hip_bfloat16*)w; w += (size_t)192 * 64 * 2;   // 24KB
    __hip_bfloat16* W1xg = (__hip_bfloat16*)w; w += (size_t)192 * 64 * 2;   // 24KB
    float*          gh1T = (float*)w;          w += (size_t)192 * kM * 4;   // 384KB
    __hip_bfloat16* BwNh = (__hip_bfloat16*)w; w += (size_t)2048 * 32 * 2;  // 128KB
    __hip_bfloat16* CwB  = (__hip_bfloat16*)w; w += (size_t)kC * kRD * kD * 2; // 32KB

    k_initHc<<<16384, 256, 0, stream>>>(Hini, HcG);
    k_h1b<<<128, 256, 0, stream>>>(Hini, H1b);
    k_gh1T<<<384, 256, 0, stream>>>(Hini, wh1, bh1, gh1T);
    k_packW<<<48, 256, 0, stream>>>(wh0, wx1, W0g, W1xg);
    k_buildGT<<<1024, 256, 0, stream>>>(G, BT);
    k_norm_aw<<<64, 64, 0, stream>>>(A_v, A_g, BT);
    k_norm_bw<<<8, 256, 0, stream>>>(B_v, B_g, B_b, BwNh);
    k_norm_cw<<<128, 64, 0, stream>>>(C_v, C_g, CwB);

    for (int t = 0; t < kW; t++) {
        k_gru<<<dim3(128, 4), 512, 0, stream>>>(x, HcG, H1b, W0g, W1xg, gh1T,
                                                wx0, bx0, bh0, bx1, XPT, t);
        k_tail<<<dim3(128, 8), 256, 0, stream>>>(XPT, BT, A_b, BwNh, CwB,
                                                 C_b, FR_w, FR_b, out, t);
    }
}

// Round 11
// 3138.504 us; speedup vs baseline: 1.2323x; 1.2323x over previous
//
#include <hip/hip_runtime.h>
#include <hip/hip_bf16.h>

// Problem constants
constexpr int kB  = 128;   // batch
constexpr int kW  = 64;    // time steps
constexpr int kM  = 512;   // "major" dim
constexpr int kH  = 64;    // GRU hidden
constexpr int kC  = 4;
constexpr int kLR = 16;
constexpr int kRD = 32;
constexpr int kD  = 128;   // L*H
constexpr int kNC = kB * kM;      // 65536 cells
constexpr int kN  = kM + kC * kLR; // 576 GEMM cols (G | Aw^T)

typedef __attribute__((ext_vector_type(8))) short bf16x8;
typedef __attribute__((ext_vector_type(4))) float f32x4;

__device__ __forceinline__ float sigmf(float v) { return 1.f / (1.f + __expf(-v)); }
__device__ __forceinline__ float tanhf2(float v) { float e = __expf(2.f * v); return 1.f - 2.f / (e + 1.f); }

__device__ __forceinline__ unsigned short f2bfu(float f) {
    union { __hip_bfloat16 h; unsigned short u; } cv; cv.h = __float2bfloat16(f); return cv.u;
}
__device__ __forceinline__ float bfu2f(unsigned short s) {
    return __uint_as_float(((unsigned)s) << 16);
}

__device__ __forceinline__ void gl_lds16(const void* g, void* s) {
    __builtin_amdgcn_global_load_lds(
        (const __attribute__((address_space(1))) void*)(g),
        (__attribute__((address_space(3))) void*)(s), 16, 0, 0);
}

// ---------------- prologue kernels ----------------

// HcG[cell][j] = bf16(H_init[0, m, j])   (cell = b*512 + m)
__global__ void k_initHc(const float* __restrict__ Hini, __hip_bfloat16* __restrict__ HcG) {
    int id = blockIdx.x * 256 + threadIdx.x;          // 65536*64
    int cell = id >> 6, j = id & 63;
    int m = cell & (kM - 1);
    HcG[id] = __float2bfloat16(Hini[m * kH + j]);
}

// H1b[m][j] = bf16(H_init[1, m, j])
__global__ void k_h1b(const float* __restrict__ Hini, __hip_bfloat16* __restrict__ H1b) {
    int id = blockIdx.x * 256 + threadIdx.x;          // 512*64
    H1b[id] = __float2bfloat16(Hini[(kM + (id >> 6)) * kH + (id & 63)]);
}

// gh1T[k][m] = bh1[k] + sum_j H_init[1,m,j] * wh1[k,j]   (f32, fixed over t)
__global__ void k_gh1T(const float* __restrict__ Hini, const float* __restrict__ wh1,
                       const float* __restrict__ bh1, float* __restrict__ gh1T) {
    int id = blockIdx.x * 256 + threadIdx.x;          // 192*512
    int k = id >> 9, m = id & (kM - 1);
    float acc = bh1[k];
    #pragma unroll
    for (int j = 0; j < kH; j++)
        acc = fmaf(Hini[(kM + m) * kH + j], wh1[k * kH + j], acc);
    gh1T[id] = acc;
}

// W0g[192][64] = bf16(wh0); W1x[192][64] = bf16(wx1)
__global__ void k_packW(const float* __restrict__ wh0, const float* __restrict__ wx1,
                        __hip_bfloat16* __restrict__ W0g, __hip_bfloat16* __restrict__ W1x) {
    int id = blockIdx.x * 256 + threadIdx.x;          // 192*64 = 12288
    W0g[id] = __float2bfloat16(wh0[id]);
    W1x[id] = __float2bfloat16(wx1[id]);
}

// BT[n][k] = G[k][n] in bf16 for n<512 (GEMM B pre-transposed, k contiguous)
__global__ void k_buildGT(const float* __restrict__ G, __hip_bfloat16* __restrict__ BT) {
    int id = blockIdx.x * 256 + threadIdx.x;          // 512*512
    int n = id >> 9, k = id & (kM - 1);
    BT[n * kM + k] = __float2bfloat16(G[k * kM + n]);
}

// weight-norm A into BT rows 512..575: BT[512+cl][m] = A_g*A_v/||A_v|| (bf16)
__global__ void k_norm_aw(const float* __restrict__ Av, const float* __restrict__ Ag,
                          __hip_bfloat16* __restrict__ BT) {
    int row = blockIdx.x;        // 0..63 = c*16+l
    int lane = threadIdx.x;      // 64
    float v[8]; float s = 0.f;
    #pragma unroll
    for (int q = 0; q < 8; q++) { v[q] = Av[row * kM + q * 64 + lane]; s += v[q] * v[q]; }
    #pragma unroll
    for (int off = 32; off > 0; off >>= 1) s += __shfl_down(s, off);
    s = __shfl(s, 0);
    float scale = Ag[row] / sqrtf(s);
    #pragma unroll
    for (int q = 0; q < 8; q++)
        BT[(kM + row) * kM + q * 64 + lane] = __float2bfloat16(v[q] * scale);
}

// weight-norm B -> bf16 [c*512+m][32]: l<16 = Bw, l==16 = B_b, rest 0
__global__ void k_norm_bw(const float* __restrict__ Bv, const float* __restrict__ Bg,
                          const float* __restrict__ Bb, __hip_bfloat16* __restrict__ BwNh) {
    int row = blockIdx.x * 256 + threadIdx.x;   // 0..2047 = c*512+m
    float v[16]; float s = 0.f;
    #pragma unroll
    for (int l = 0; l < 16; l++) { v[l] = Bv[row * 16 + l]; s += v[l] * v[l]; }
    float scale = Bg[row] / sqrtf(s);
    #pragma unroll
    for (int l = 0; l < 16; l++) BwNh[row * 32 + l] = __float2bfloat16(v[l] * scale);
    BwNh[row * 32 + 16] = __float2bfloat16(Bb[row]);
    #pragma unroll
    for (int l = 17; l < 32; l++) BwNh[row * 32 + l] = __float2bfloat16(0.f);
}

// weight-norm C -> bf16 [c*32+r][128 d] (natural C_v layout)
__global__ void k_norm_cw(const float* __restrict__ Cv, const float* __restrict__ Cg,
                          __hip_bfloat16* __restrict__ CwB) {
    int row = blockIdx.x;        // 0..127 = c*32+r
    int lane = threadIdx.x;      // 64
    float v0 = Cv[row * kD + lane], v1 = Cv[row * kD + 64 + lane];
    float s = v0 * v0 + v1 * v1;
    #pragma unroll
    for (int off = 32; off > 0; off >>= 1) s += __shfl_down(s, off);
    s = __shfl(s, 0);
    float scale = Cg[row] / sqrtf(s);
    CwB[row * kD + lane] = __float2bfloat16(v0 * scale);
    CwB[row * kD + 64 + lane] = __float2bfloat16(v1 * scale);
}

// ---------------- MFMA GRU step (R9 version, unchanged) ----------------
__global__ __launch_bounds__(512) void k_gru(
    const float* __restrict__ x,
    __hip_bfloat16* __restrict__ HcG,        // [65536][64] state in/out
    const __hip_bfloat16* __restrict__ H1b,  // [512][64] h01 table
    const __hip_bfloat16* __restrict__ W0g,  // [192][64] wh0
    const __hip_bfloat16* __restrict__ W1x,  // [192][64] wx1
    const float* __restrict__ gh1T,          // [192][512] f32
    const float* __restrict__ wx0, const float* __restrict__ bx0,
    const float* __restrict__ bh0, const float* __restrict__ bx1,
    __hip_bfloat16* __restrict__ XPT, int t)
{
    __shared__ __align__(16) short W0s[192 * 64];    // 24KB
    __shared__ __align__(16) short W1s[192 * 64];    // 24KB
    __shared__ __align__(16) short HlS[128 * 64];    // 16KB
    __shared__ float xsh[128];

    const int tid = threadIdx.x;
    const int w = tid >> 6, lane = tid & 63;
    const int lr = lane & 15, lq = lane >> 4;
    const int b = blockIdx.x;
    const int mBlk = blockIdx.y * 128;
    const unsigned short* HcU = (const unsigned short*)HcG;
    const unsigned short* H1U = (const unsigned short*)H1b;
    const size_t cellBase = (size_t)b * kM + mBlk;

    #pragma unroll
    for (int it = 0; it < 3; it++) {                  // W0s: 1536 chunks
        int cid = it * 512 + tid; int row = cid >> 3, c = cid & 7;
        gl_lds16(W0g + row * 64 + ((c ^ (row & 7)) * 8), W0s + cid * 8);
    }
    #pragma unroll
    for (int it = 0; it < 3; it++) {                  // W1s: 1536 chunks
        int cid = it * 512 + tid; int row = cid >> 3, c = cid & 7;
        gl_lds16(W1x + row * 64 + ((c ^ (row & 7)) * 8), W1s + cid * 8);
    }
    if (tid < 128) xsh[tid] = x[((size_t)b * kW + t) * kM + mBlk + tid];
    __syncthreads();

    const int cl = w * 16 + lr;      // A-fragment row (cell) for this lane

    // ---- Layer 0 MFMA: 12 gate-tiles x K=64 (h_prev direct from global) ----
    bf16x8 a0[2];
    a0[0] = *(const bf16x8*)&HcU[(cellBase + cl) * 64 + lq * 8];
    a0[1] = *(const bf16x8*)&HcU[(cellBase + cl) * 64 + (4 + lq) * 8];
    f32x4 aR[4] = {}, aZ[4] = {}, aN[4] = {};
    #pragma unroll
    for (int kc = 0; kc < 2; kc++) {
        #pragma unroll
        for (int gt = 0; gt < 4; gt++) {
            const int gR = gt * 16 + lr;
            const int gZ = 64 + gt * 16 + lr;
            const int gN = 128 + gt * 16 + lr;
            bf16x8 bR = *(const bf16x8*)&W0s[gR * 64 + (((kc * 4 + lq) ^ (gR & 7)) * 8)];
            bf16x8 bZ = *(const bf16x8*)&W0s[gZ * 64 + (((kc * 4 + lq) ^ (gZ & 7)) * 8)];
            bf16x8 bN = *(const bf16x8*)&W0s[gN * 64 + (((kc * 4 + lq) ^ (gN & 7)) * 8)];
            aR[gt] = __builtin_amdgcn_mfma_f32_16x16x32_bf16(a0[kc], bR, aR[gt], 0, 0, 0);
            aZ[gt] = __builtin_amdgcn_mfma_f32_16x16x32_bf16(a0[kc], bZ, aZ[gt], 0, 0, 0);
            aN[gt] = __builtin_amdgcn_mfma_f32_16x16x32_bf16(a0[kc], bN, aN[gt], 0, 0, 0);
        }
    }

    // ---- Layer 0 combine ----
    #pragma unroll
    for (int gt = 0; gt < 4; gt++) {
        const int i = gt * 16 + lr;
        const float wxr = wx0[i], wxz = wx0[64 + i], wxn = wx0[128 + i];
        const float bsr = bx0[i] + bh0[i];
        const float bsz = bx0[64 + i] + bh0[64 + i];
        const float bxn = bx0[128 + i], bhn = bh0[128 + i];
        unsigned short hu[4];
        #pragma unroll
        for (int r2 = 0; r2 < 4; r2++) {
            const int clr = w * 16 + lq * 4 + r2;
            const float xv = xsh[clr];
            float rr = sigmf(aR[gt][r2] + bsr + xv * wxr);
            float zz = sigmf(aZ[gt][r2] + bsz + xv * wxz);
            float nn = tanhf2(bxn + xv * wxn + rr * (aN[gt][r2] + bhn));
            float hp = bfu2f(HcU[(cellBase + clr) * 64 + i]);  // own wave's cell: no hazard
            float h1 = nn + zz * (hp - nn);
            unsigned short u = f2bfu(h1);
            HlS[clr * 64 + (((i >> 3) ^ (clr & 7)) * 8) + (i & 7)] = (short)u;
            hu[r2] = u;
        }
        ushort4 pk; pk.x = hu[0]; pk.y = hu[1]; pk.z = hu[2]; pk.w = hu[3];
        *(ushort4*)((unsigned short*)XPT + (size_t)(b * 128 + i) * kM + mBlk + w * 16 + lq * 4) = pk;
    }

    // ---- Layer 1 MFMA: K=64 (h1 @ wx1^T); hidden side via gh1T table ----
    bf16x8 a1[2];
    a1[0] = *(const bf16x8*)&HlS[cl * 64 + ((lq ^ (cl & 7)) * 8)];
    a1[1] = *(const bf16x8*)&HlS[cl * 64 + (((4 + lq) ^ (cl & 7)) * 8)];
    f32x4 cR[4] = {}, cZ[4] = {}, cN[4] = {};
    #pragma unroll
    for (int kc = 0; kc < 2; kc++) {
        #pragma unroll
        for (int gt = 0; gt < 4; gt++) {
            const int gR = gt * 16 + lr;
            const int gZ = 64 + gt * 16 + lr;
            const int gN = 128 + gt * 16 + lr;
            bf16x8 bR = *(const bf16x8*)&W1s[gR * 64 + (((kc * 4 + lq) ^ (gR & 7)) * 8)];
            bf16x8 bZ = *(const bf16x8*)&W1s[gZ * 64 + (((kc * 4 + lq) ^ (gZ & 7)) * 8)];
            bf16x8 bN = *(const bf16x8*)&W1s[gN * 64 + (((kc * 4 + lq) ^ (gN & 7)) * 8)];
            cR[gt] = __builtin_amdgcn_mfma_f32_16x16x32_bf16(a1[kc], bR, cR[gt], 0, 0, 0);
            cZ[gt] = __builtin_amdgcn_mfma_f32_16x16x32_bf16(a1[kc], bZ, cZ[gt], 0, 0, 0);
            cN[gt] = __builtin_amdgcn_mfma_f32_16x16x32_bf16(a1[kc], bN, cN[gt], 0, 0, 0);
        }
    }

    // ---- Layer 1 combine (gh1T f32 table holds H1init@wh1^T + bh1) ----
    const int mb4 = mBlk + w * 16 + lq * 4;
    #pragma unroll
    for (int gt = 0; gt < 4; gt++) {
        const int i = gt * 16 + lr;
        const float bxr = bx1[i], bxz = bx1[64 + i], bxn = bx1[128 + i];
        f32x4 gr4 = *(const f32x4*)&gh1T[(size_t)i * kM + mb4];
        f32x4 gz4 = *(const f32x4*)&gh1T[(size_t)(64 + i) * kM + mb4];
        f32x4 gn4 = *(const f32x4*)&gh1T[(size_t)(128 + i) * kM + mb4];
        unsigned short hu[4];
        #pragma unroll
        for (int r2 = 0; r2 < 4; r2++) {
            const int clr = w * 16 + lq * 4 + r2;
            float rr = sigmf(cR[gt][r2] + bxr + gr4[r2]);
            float zz = sigmf(cZ[gt][r2] + bxz + gz4[r2]);
            float nn = tanhf2(cN[gt][r2] + bxn + rr * gn4[r2]);
            float h01 = bfu2f(H1U[(size_t)(mBlk + clr) * 64 + i]);
            float h2 = nn + zz * (h01 - nn);
            unsigned short u = f2bfu(h2);
            hu[r2] = u;
            ((unsigned short*)HcG)[(cellBase + clr) * 64 + i] = u;   // next-step state
        }
        ushort4 pk; pk.x = hu[0]; pk.y = hu[1]; pk.z = hu[2]; pk.w = hu[3];
        *(ushort4*)((unsigned short*)XPT + (size_t)(b * 128 + 64 + i) * kM + mBlk + w * 16 + lq * 4) = pk;
    }
}

// ---------------- fused GEMM + tail ----------------
// Grid dim3(128 b, 4 mseg) = 512 blocks, 512 thr = 8 waves (2 wm x 4 wn),
// wave tile 64x48. N=192/block: 128 unique m-cols + 64 a-cols (4x redundant
// instead of 8x). BK=64 double-buffer via gl_lds16 (R7 structure). 80KB LDS,
// 2 blocks/CU = 4 waves/SIMD.
__global__ __launch_bounds__(512, 4) void k_tail(
    const __hip_bfloat16* __restrict__ X,    // XPT [b*128+d][512]
    const __hip_bfloat16* __restrict__ BT,   // [576][512]
    const float* __restrict__ Ab,
    const __hip_bfloat16* __restrict__ BwNh, // [c*512+m][32]
    const __hip_bfloat16* __restrict__ CwB,  // [c*32+r][128]
    const float* __restrict__ Cb, const float* __restrict__ FRw,
    const float* __restrict__ FRb, float* __restrict__ OUT, int t)
{
    __shared__ __align__(16) short SM[40960];        // 80KB
    // buf(i) = SM + i*20480: A [128 rows][64 k] (8192 sh) + B [192 cols][64 k] (12288 sh)
    short* xp0L = SM;                // [128 m][128 d] 32KB (aliases buf0)
    short* aL   = SM + 16384;        // [128 d][64 cl] 16KB
    short* Xr   = SM + 24576;        // [8 waves][16 m][128 d] 32KB

    const int tid = threadIdx.x;
    const int b = blockIdx.x, mseg = blockIdx.y;
    const int w = tid >> 6, lane = tid & 63;
    const int lr = lane & 15, lq = lane >> 4;
    const int wm = w >> 2, wn = w & 3;

    f32x4 acc[4][3] = {};
    const __hip_bfloat16* Xb = X + (size_t)b * 128 * kM;

    auto STAGE = [&](int kk, int buf) {
        short* AsB = SM + buf * 20480;
        short* BsB = AsB + 8192;
        #pragma unroll
        for (int it = 0; it < 2; it++) {             // A: 128 rows x 8 chunks = 1024
            int cid = it * 512 + tid;
            int row = cid >> 3, ch = cid & 7;
            int cg = ch ^ (row & 7);
            gl_lds16(Xb + (size_t)row * kM + kk + cg * 8, AsB + cid * 8);
        }
        #pragma unroll
        for (int it = 0; it < 3; it++) {             // B: 192 cols x 8 chunks = 1536
            int cid = it * 512 + tid;
            int j = cid >> 3, ch = cid & 7;
            int cg = ch ^ (j & 7);
            int n = (j < 128) ? (mseg * 128 + j) : (384 + j);   // a-cols 512..575
            gl_lds16(BT + (size_t)n * kM + kk + cg * 8, BsB + cid * 8);
        }
    };

    STAGE(0, 0);
    __syncthreads();          // buf0 ready (vmcnt drained)

    int cur = 0;
    for (int ki = 0; ki < 8; ki++) {
        if (ki < 7) STAGE((ki + 1) * 64, cur ^ 1);   // loads in flight over compute
        const short* AsB = SM + cur * 20480;
        const short* BsB = AsB + 8192;
        #pragma unroll
        for (int w2 = 0; w2 < 2; w2++) {
            bf16x8 af[4], bfr[3];
            #pragma unroll
            for (int fi = 0; fi < 4; fi++) {
                int row = wm * 64 + fi * 16 + lr;
                af[fi] = *(const bf16x8*)&AsB[row * 64 + (((w2 * 4 + lq) ^ (row & 7)) * 8)];
            }
            #pragma unroll
            for (int fj = 0; fj < 3; fj++) {
                int col = wn * 48 + fj * 16 + lr;
                bfr[fj] = *(const bf16x8*)&BsB[col * 64 + (((w2 * 4 + lq) ^ (col & 7)) * 8)];
            }
            #pragma unroll
            for (int fi = 0; fi < 4; fi++)
                #pragma unroll
                for (int fj = 0; fj < 3; fj++)
                    acc[fi][fj] = __builtin_amdgcn_mfma_f32_16x16x32_bf16(
                        af[fi], bfr[fj], acc[fi][fj], 0, 0, 0);
        }
        __syncthreads();      // waves done with buf[cur]; next buf staged
        cur ^= 1;
    }

    // ---- scatter C tile to LDS (GEMM buffers now dead; aliased) ----
    #pragma unroll
    for (int fj = 0; fj < 3; fj++) {
        const int colg = wn * 48 + fj * 16 + lr;     // 0..191
        if (colg < 128) {
            // m-col -> relu -> xp0L[m][d] (packed 4 d per uint2, chunk-XOR by m&7)
            #pragma unroll
            for (int fi = 0; fi < 4; fi++) {
                const int d0 = wm * 64 + fi * 16 + lq * 4;
                const int c16 = d0 >> 3, half = lq & 1;
                unsigned lo = (unsigned)f2bfu(fmaxf(acc[fi][fj][0], 0.f)) |
                              ((unsigned)f2bfu(fmaxf(acc[fi][fj][1], 0.f)) << 16);
                unsigned hi = (unsigned)f2bfu(fmaxf(acc[fi][fj][2], 0.f)) |
                              ((unsigned)f2bfu(fmaxf(acc[fi][fj][3], 0.f)) << 16);
                uint2 pk; pk.x = lo; pk.y = hi;
                *(uint2*)&xp0L[colg * 128 + ((c16 ^ (colg & 7)) * 8) + half * 4] = pk;
            }
        } else {
            // a-col -> +A_b -> aL[d][cl] (scalar bf16, chunk-XOR by d&7)
            const int clc = colg - 128;
            const float ab = Ab[clc];
            #pragma unroll
            for (int fi = 0; fi < 4; fi++) {
                #pragma unroll
                for (int r = 0; r < 4; r++) {
                    const int d = wm * 64 + fi * 16 + lq * 4 + r;
                    aL[d * 64 + (((clc >> 3) ^ (d & 7)) * 8) + (clc & 7)] =
                        (short)f2bfu(acc[fi][fj][r] + ab);
                }
            }
        }
    }
    __syncthreads();

    // ---- tail: wave (c = w&3, m-half = w>>2); 64 m per wave ----
    const int c = w & 3;
    const int mhalf = w >> 2;
    bf16x8 af2[8];
    #pragma unroll
    for (int dt = 0; dt < 8; dt++) {
        bf16x8 v = {};
        const int d = dt * 16 + lr;
        if (lq < 2) {
            v = *(const bf16x8*)&aL[d * 64 + (((c * 2 + lq) ^ (d & 7)) * 8)];
        } else if (lq == 2) {
            v[0] = (short)0x3F80;          // 1.0 at k=16 -> bias column
        }
        af2[dt] = v;
    }
    bf16x8 cwf[2][4];
    #pragma unroll
    for (int rt = 0; rt < 2; rt++)
        #pragma unroll
        for (int s = 0; s < 4; s++)
            cwf[rt][s] = *(const bf16x8*)&CwB[((size_t)(c * kRD + rt * 16 + lr)) * kD + s * 32 + lq * 8];
    const float cbv0 = Cb[c * kRD + lr];
    const float cbv1 = Cb[c * kRD + 16 + lr];
    short* Xrw = Xr + w * 2048;

    for (int mt = 0; mt < 4; mt++) {
        const int mg = mseg * 128 + mhalf * 64 + mt * 16 + lr;   // global m (B-frag col)
        bf16x8 bf1 = *(const bf16x8*)&BwNh[((size_t)c * kM + mg) * 32 + lq * 8];
        f32x4 acc1[8] = {};
        #pragma unroll
        for (int dt = 0; dt < 8; dt++)
            acc1[dt] = __builtin_amdgcn_mfma_f32_16x16x32_bf16(af2[dt], bf1, acc1[dt], 0, 0, 0);

        // + x_p0, relu, pack -> Xr (wave-private)
        const int mlT = mhalf * 64 + mt * 16 + lr;               // xp0L row (0..127)
        #pragma unroll
        for (int dt = 0; dt < 8; dt++) {
            const int c16 = dt * 2 + (lq >> 1), half = lq & 1;
            uint2 xv = *(const uint2*)&xp0L[mlT * 128 + ((c16 ^ (mlT & 7)) * 8) + half * 4];
            float x0 = bfu2f((unsigned short)(xv.x & 0xFFFF));
            float x1 = bfu2f((unsigned short)(xv.x >> 16));
            float x2 = bfu2f((unsigned short)(xv.y & 0xFFFF));
            float x3 = bfu2f((unsigned short)(xv.y >> 16));
            unsigned lo = (unsigned)f2bfu(fmaxf(acc1[dt][0] + x0, 0.f)) |
                          ((unsigned)f2bfu(fmaxf(acc1[dt][1] + x1, 0.f)) << 16);
            unsigned hi = (unsigned)f2bfu(fmaxf(acc1[dt][2] + x2, 0.f)) |
                          ((unsigned)f2bfu(fmaxf(acc1[dt][3] + x3, 0.f)) << 16);
            uint2 pk; pk.x = lo; pk.y = hi;
            *(uint2*)&Xrw[lr * 128 + ((c16 ^ (lr & 7)) * 8) + half * 4] = pk;
        }

        // stage 2: y-logits + sigmoid + FR dot
        bf16x8 xa[4];
        #pragma unroll
        for (int s = 0; s < 4; s++)
            xa[s] = *(const bf16x8*)&Xrw[lr * 128 + (((s * 4 + lq) ^ (lr & 7)) * 8)];
        float po0 = 0.f, po1 = 0.f, po2 = 0.f, po3 = 0.f;
        const int mrow = mseg * 128 + mhalf * 64 + mt * 16 + lq * 4;
        #pragma unroll
        for (int rt = 0; rt < 2; rt++) {
            f32x4 a2 = {};
            #pragma unroll
            for (int s = 0; s < 4; s++)
                a2 = __builtin_amdgcn_mfma_f32_16x16x32_bf16(xa[s], cwf[rt][s], a2, 0, 0, 0);
            const float cb = rt ? cbv1 : cbv0;
            const int r = rt * 16 + lr;
            po0 = fmaf(sigmf(a2[0] + cb), FRw[((size_t)c * kM + mrow + 0) * kRD + r], po0);
            po1 = fmaf(sigmf(a2[1] + cb), FRw[((size_t)c * kM + mrow + 1) * kRD + r], po1);
            po2 = fmaf(sigmf(a2[2] + cb), FRw[((size_t)c * kM + mrow + 2) * kRD + r], po2);
            po3 = fmaf(sigmf(a2[3] + cb), FRw[((size_t)c * kM + mrow + 3) * kRD + r], po3);
        }
        #pragma unroll
        for (int off = 8; off > 0; off >>= 1) {
            po0 += __shfl_xor(po0, off);
            po1 += __shfl_xor(po1, off);
            po2 += __shfl_xor(po2, off);
            po3 += __shfl_xor(po3, off);
        }
        if (lr == 0) {
            const float* frb = &FRb[c * kM + mrow];
            float4 o;
            o.x = po0 + frb[0]; o.y = po1 + frb[1];
            o.z = po2 + frb[2]; o.w = po3 + frb[3];
            *(float4*)&OUT[((size_t)(c * kB + b) * kW + t) * kM + mrow] = o;
        }
    }
}

// ---------------- launch ----------------
extern "C" void kernel_launch(void* const* d_in, const int* in_sizes, int n_in,
                              void* d_out, int out_size, void* d_ws, size_t ws_size,
                              hipStream_t stream) {
    const float* x    = (const float*)d_in[0];
    const float* Hini = (const float*)d_in[1];
    const float* G    = (const float*)d_in[2];
    const float* wx0  = (const float*)d_in[3];
    const float* wh0  = (const float*)d_in[4];
    const float* bx0  = (const float*)d_in[5];
    const float* bh0  = (const float*)d_in[6];
    const float* wx1  = (const float*)d_in[7];
    const float* wh1  = (const float*)d_in[8];
    const float* bx1  = (const float*)d_in[9];
    const float* bh1  = (const float*)d_in[10];
    const float* A_v  = (const float*)d_in[11];
    const float* A_g  = (const float*)d_in[12];
    const float* A_b  = (const float*)d_in[13];
    const float* B_v  = (const float*)d_in[14];
    const float* B_g  = (const float*)d_in[15];
    const float* B_b  = (const float*)d_in[16];
    const float* C_v  = (const float*)d_in[17];
    const float* C_g  = (const float*)d_in[18];
    const float* C_b  = (const float*)d_in[19];
    const float* FR_w = (const float*)d_in[20];
    const float* FR_b = (const float*)d_in[21];
    float* out = (float*)d_out;

    char* w = (char*)d_ws;
    __hip_bfloat16* HcG  = (__hip_bfloat16*)w; w += (size_t)kNC * 64 * 2;   // 8MB
    __hip_bfloat16* XPT  = (__hip_bfloat16*)w; w += (size_t)128 * kNC * 2;  // 16MB
    __hip_bfloat16* BT   = (__hip_bfloat16*)w; w += (size_t)kN * kM * 2;    // 576KB
    __hip_bfloat16* H1b  = (__hip_bfloat16*)w; w += (size_t)kM * kH * 2;    // 64KB
    __hip_bfloat16* W0g  = (__hip_bfloat16*)w; w += (size_t)192 * 64 * 2;   // 24KB
    __hip_bfloat16* W1xg = (__hip_bfloat16*)w; w += (size_t)192 * 64 * 2;   // 24KB
    float*          gh1T = (float*)w;          w += (size_t)192 * kM * 4;   // 384KB
    __hip_bfloat16* BwNh = (__hip_bfloat16*)w; w += (size_t)2048 * 32 * 2;  // 128KB
    __hip_bfloat16* CwB  = (__hip_bfloat16*)w; w += (size_t)kC * kRD * kD * 2; // 32KB

    k_initHc<<<16384, 256, 0, stream>>>(Hini, HcG);
    k_h1b<<<128, 256, 0, stream>>>(Hini, H1b);
    k_gh1T<<<384, 256, 0, stream>>>(Hini, wh1, bh1, gh1T);
    k_packW<<<48, 256, 0, stream>>>(wh0, wx1, W0g, W1xg);
    k_buildGT<<<1024, 256, 0, stream>>>(G, BT);
    k_norm_aw<<<64, 64, 0, stream>>>(A_v, A_g, BT);
    k_norm_bw<<<8, 256, 0, stream>>>(B_v, B_g, B_b, BwNh);
    k_norm_cw<<<128, 64, 0, stream>>>(C_v, C_g, CwB);

    for (int t = 0; t < kW; t++) {
        k_gru<<<dim3(128, 4), 512, 0, stream>>>(x, HcG, H1b, W0g, W1xg, gh1T,
                                                wx0, bx0, bh0, bx1, XPT, t);
        k_tail<<<dim3(128, 4), 512, 0, stream>>>(XPT, BT, A_b, BwNh, CwB,
                                                 C_b, FR_w, FR_b, out, t);
    }
}